// Round 4
// baseline (222.403 us; speedup 1.0000x reference)
//
#include <hip/hip_runtime.h>

#define BATCH 8192
#define IN_F 4096
#define OUT_F 4096

#define NWAVES 2048          // 512 blocks x 4 waves
#define ROWS_PER_WAVE 4      // 2048 * 4 = 8192 rows

typedef float f4 __attribute__((ext_vector_type(4)));

// Persistent pipelined kernel: each wave owns 4 rows (stride 2048).
// Pipeline: reduce row k -> ISSUE row k+1 loads -> store row k.
// Next-row HBM reads stay in flight under the store burst, so chip-wide
// the read stream (the ~3 TB/s-capped side on this box) never drains
// while writes (6.7 TB/s-capable, posted) hide beneath it.
__global__ __launch_bounds__(256) void
rank1_pipe_kernel(const float* __restrict__ x, const float* __restrict__ w,
                  float* __restrict__ out) {
    const int wave = threadIdx.x >> 6;
    const int lane = threadIdx.x & 63;
    const int wid  = (blockIdx.x << 2) + wave;   // 0..2047

    const f4* w4 = reinterpret_cast<const f4*>(w);

    // prologue: issue loads for first row
    f4 buf[16];                                   // 64 VGPRs, static indices only
    {
        const f4* xp = reinterpret_cast<const f4*>(x + (size_t)wid * IN_F);
#pragma unroll
        for (int j = 0; j < 16; ++j)
            buf[j] = __builtin_nontemporal_load(&xp[j * 64 + lane]);
    }

    for (int k = 0; k < ROWS_PER_WAVE; ++k) {
        const int row = wid + k * NWAVES;

        // ---- reduce current row (compiler waits on its vmcnt here) ----
        float s0 = 0.f, s1 = 0.f, s2 = 0.f, s3 = 0.f;
#pragma unroll
        for (int j = 0; j < 16; j += 4) {
            s0 += (buf[j + 0].x + buf[j + 0].y) + (buf[j + 0].z + buf[j + 0].w);
            s1 += (buf[j + 1].x + buf[j + 1].y) + (buf[j + 1].z + buf[j + 1].w);
            s2 += (buf[j + 2].x + buf[j + 2].y) + (buf[j + 2].z + buf[j + 2].w);
            s3 += (buf[j + 3].x + buf[j + 3].y) + (buf[j + 3].z + buf[j + 3].w);
        }
        float s = (s0 + s1) + (s2 + s3);
#pragma unroll
        for (int off = 1; off < 64; off <<= 1)
            s += __shfl_xor(s, off, 64);

        // ---- issue NEXT row's loads BEFORE storing current row ----
        if (k + 1 < ROWS_PER_WAVE) {
            const f4* xn = reinterpret_cast<const f4*>(
                x + (size_t)(wid + (k + 1) * NWAVES) * IN_F);
#pragma unroll
            for (int j = 0; j < 16; ++j)
                buf[j] = __builtin_nontemporal_load(&xn[j * 64 + lane]);
        }

        // ---- store current row while next reads are in flight ----
        // w is L1-hot (16 KiB shared by all waves); out is write-once -> NT.
        f4* o4 = reinterpret_cast<f4*>(out + (size_t)row * OUT_F);
#pragma unroll
        for (int j = 0; j < 16; ++j) {
            f4 wv = w4[j * 64 + lane];
            f4 ov;
            ov.x = s * wv.x;
            ov.y = s * wv.y;
            ov.z = s * wv.z;
            ov.w = s * wv.w;
            __builtin_nontemporal_store(ov, &o4[j * 64 + lane]);
        }
    }
}

extern "C" void kernel_launch(void* const* d_in, const int* in_sizes, int n_in,
                              void* d_out, int out_size, void* d_ws, size_t ws_size,
                              hipStream_t stream) {
    const float* x = (const float*)d_in[0];   // [8192, 4096] fp32
    const float* w = (const float*)d_in[1];   // [1, 4096] fp32
    float* out = (float*)d_out;               // [8192, 4096] fp32
    rank1_pipe_kernel<<<NWAVES / 4, 256, 0, stream>>>(x, w, out);
}